// Round 6
// baseline (705.673 us; speedup 1.0000x reference)
//
#include <hip/hip_runtime.h>
#include <hip/hip_bf16.h>
#include <math.h>

#define NN    30000
#define MPAD  30080   // 235*128, padded row count for bounds-check-free GEMM
#define EE    300000
#define ETOT  330000
#define GG    128
#define IND   128
#define HIDD  64
#define NHEAD 4
#define CC    256     // HEADS*HID
#define NCL   10
#define EPSBN 1e-5f
#define SLOPE 0.2f

typedef __attribute__((ext_vector_type(8))) __bf16 bf16x8;
typedef __attribute__((ext_vector_type(4))) float f32x4;
typedef __attribute__((ext_vector_type(2))) float f32x2;

__device__ inline float b2f(unsigned u16) {
    union { unsigned i; float f; } c; c.i = u16 << 16; return c.f;
}
__device__ inline unsigned short f2b(float f) {
    __hip_bfloat16 b = __float2bfloat16(f);
    unsigned short u; __builtin_memcpy(&u, &b, 2); return u;
}
__device__ inline f32x2 upk(unsigned u) {     // 2 packed bf16 -> f32x2
    union { unsigned i; float f; } lo, hi;
    lo.i = u << 16;
    hi.i = u & 0xffff0000u;
    f32x2 r; r.x = lo.f; r.y = hi.f; return r;
}
__device__ inline void unpack8(uint4 u, float* f) {
    f[0] = b2f(u.x & 0xffffu); f[1] = b2f(u.x >> 16);
    f[2] = b2f(u.y & 0xffffu); f[3] = b2f(u.y >> 16);
    f[4] = b2f(u.z & 0xffffu); f[5] = b2f(u.z >> 16);
    f[6] = b2f(u.w & 0xffffu); f[7] = b2f(u.w >> 16);
}

// ---------------- fused: degree histogram + weight prep + x conversion ----------------
struct WPtrs { const float* wl[4]; const float* wr[4]; };

__global__ void k_setup(const int* __restrict__ ei, int* __restrict__ deg,
                        WPtrs p, const float* __restrict__ x,
                        __hip_bfloat16* __restrict__ wt, __hip_bfloat16* __restrict__ hb) {
    int id = blockIdx.x * 256 + threadIdx.x;
    if (id < ETOT) {
        int d = (id < EE) ? ei[EE + id] : (id - EE);
        atomicAdd(&deg[d], 1);
        return;
    }
    int id1 = id - ETOT;
    if (id1 < 65536) {                       // layer 0 W: [512][128]
        int n = id1 >> 7, k = id1 & 127;
        float v = (n < 256) ? p.wl[0][(size_t)k * 256 + n] : p.wr[0][(size_t)k * 256 + n - 256];
        wt[id1] = __float2bfloat16(v);
    } else if (id1 < 458752) {               // layers 1-3 W: [512][256]
        int id2 = id1 - 65536;
        int li = 1 + (id2 >> 17);
        int r = id2 & 131071;
        int n = r >> 8, k = r & 255;
        float v = (n < 256) ? p.wl[li][(size_t)k * 256 + n] : p.wr[li][(size_t)k * 256 + n - 256];
        wt[id1] = __float2bfloat16(v);
    } else {
        int id2 = id1 - 458752;
        if (id2 < NN * IND) hb[id2] = __float2bfloat16(x[id2]);
    }
}

__global__ void k_scan(const int* __restrict__ deg, int* __restrict__ rowptr,
                       int* __restrict__ cursor) {
    const int PER = 30;
    int t = threadIdx.x;
    int base = t * PER;
    int loc[PER];
    int s = 0;
    #pragma unroll
    for (int j = 0; j < PER; ++j) {
        int v = (base + j < NN) ? deg[base + j] : 0;
        loc[j] = s; s += v;
    }
    int lane = t & 63, wid = t >> 6;
    int v = s;
    #pragma unroll
    for (int d = 1; d < 64; d <<= 1) {
        int u = __shfl_up(v, d, 64);
        if (lane >= d) v += u;
    }
    __shared__ int wsum[16], woff[16];
    if (lane == 63) wsum[wid] = v;
    __syncthreads();
    if (t == 0) { int a = 0; for (int w2 = 0; w2 < 16; ++w2) { woff[w2] = a; a += wsum[w2]; } }
    __syncthreads();
    int excl = woff[wid] + (v - s);
    #pragma unroll
    for (int j = 0; j < PER; ++j) {
        int idx = base + j;
        if (idx <= NN) { int val = excl + loc[j]; rowptr[idx] = val; cursor[idx] = val; }
    }
}

__global__ void k_scatter(const int* __restrict__ ei, int* __restrict__ cursor,
                          int* __restrict__ csrc) {
    int e = blockIdx.x * blockDim.x + threadIdx.x;
    if (e >= ETOT) return;
    int s, d;
    if (e < EE) { s = ei[e]; d = ei[EE + e]; } else { s = e - EE; d = s; }
    int pos = atomicAdd(&cursor[d], 1);
    csrc[pos] = s;
}

// ---------------- bf16 MFMA GEMM, BK=64: [MPAD,K]@[K,512] -> xlb, xrb (bf16) ----------------
// LDS 2x18KB, 2 barriers per 64-k (half the barrier count of BK=32).
template<int K>
__global__ __launch_bounds__(256) void k_gemm_mfma(
        const __hip_bfloat16* __restrict__ A, const __hip_bfloat16* __restrict__ Wt,
        __hip_bfloat16* __restrict__ xlb, __hip_bfloat16* __restrict__ xrb) {
    __shared__ __bf16 As[128 * 72];   // [row][k0..63] pad 64->72 (144B stride, 16B aligned)
    __shared__ __bf16 Bs[128 * 72];
    const int t = threadIdx.x;
    const int row0 = blockIdx.x * 128;
    const int col0 = blockIdx.y * 128;
    const int wv = t >> 6, lane = t & 63;
    const int wm = (wv & 1) * 64, wn = (wv >> 1) * 64;
    const int lm = lane & 15, lq = lane >> 4;
    const int sr = t >> 1;              // staging row 0..127
    const int sh = (t & 1) * 32;        // staging col offset (elements)
    uint4 va[4], vb[4];
    #pragma unroll
    for (int i = 0; i < 4; ++i) {
        va[i] = *(const uint4*)&A [(size_t)(row0 + sr) * K + sh + i * 8];
        vb[i] = *(const uint4*)&Wt[(size_t)(col0 + sr) * K + sh + i * 8];
    }
    f32x4 acc[4][4] = {};
    for (int k0 = 0; k0 < K; k0 += 64) {
        #pragma unroll
        for (int i = 0; i < 4; ++i) {
            *(uint4*)&As[sr * 72 + sh + i * 8] = va[i];
            *(uint4*)&Bs[sr * 72 + sh + i * 8] = vb[i];
        }
        __syncthreads();
        if (k0 + 64 < K) {
            int kn = k0 + 64;
            #pragma unroll
            for (int i = 0; i < 4; ++i) {
                va[i] = *(const uint4*)&A [(size_t)(row0 + sr) * K + kn + sh + i * 8];
                vb[i] = *(const uint4*)&Wt[(size_t)(col0 + sr) * K + kn + sh + i * 8];
            }
        }
        #pragma unroll
        for (int kk = 0; kk < 2; ++kk) {
            bf16x8 af[4], bfr[4];
            #pragma unroll
            for (int i = 0; i < 4; ++i) {
                af[i]  = *(bf16x8*)&As[(wm + i * 16 + lm) * 72 + kk * 32 + lq * 8];
                bfr[i] = *(bf16x8*)&Bs[(wn + i * 16 + lm) * 72 + kk * 32 + lq * 8];
            }
            #pragma unroll
            for (int i = 0; i < 4; ++i)
                #pragma unroll
                for (int j = 0; j < 4; ++j)
                    acc[i][j] = __builtin_amdgcn_mfma_f32_16x16x32_bf16(af[i], bfr[j], acc[i][j], 0, 0, 0);
        }
        __syncthreads();
    }
    const int crow = lq * 4;
    __hip_bfloat16* O = (blockIdx.y < 2) ? xlb : xrb;
    const int cbase = (blockIdx.y & 1) * 128 + wn;
    #pragma unroll
    for (int j = 0; j < 4; ++j) {
        int oc = cbase + j * 16 + lm;
        #pragma unroll
        for (int i = 0; i < 4; ++i) {
            int grow = row0 + wm + i * 16 + crow;
            #pragma unroll
            for (int r = 0; r < 4; ++r)
                O[(size_t)(grow + r) * CC + oc] = __float2bfloat16(acc[i][j][r]);
        }
    }
}

// ---------------- GATv2: one wave per dst, 2 edges/iter, packed-f32 math ----------------
template<bool CONCAT>
__global__ __launch_bounds__(256) void k_gat(const __hip_bfloat16* __restrict__ xlb,
        const __hip_bfloat16* __restrict__ xrb, const int* __restrict__ rowptr,
        const int* __restrict__ csrc, const float* __restrict__ att,
        __hip_bfloat16* __restrict__ outb, float* __restrict__ outf) {
    const int wv = threadIdx.x >> 6, lane = threadIdx.x & 63;
    const int n = blockIdx.x * 4 + wv;
    if (n >= NN) return;
    const int sub = lane >> 5, l5 = lane & 31;
    const float4* att4 = (const float4*)att;
    float4 a0 = att4[l5 * 2], a1 = att4[l5 * 2 + 1];
    f32x2 aw[4];
    aw[0].x = a0.x; aw[0].y = a0.y; aw[1].x = a0.z; aw[1].y = a0.w;
    aw[2].x = a1.x; aw[2].y = a1.y; aw[3].x = a1.z; aw[3].y = a1.w;
    const uint4* xl4 = (const uint4*)xlb;
    const uint4* xr4 = (const uint4*)xrb;
    uint4 xru = xr4[(size_t)n * 32 + l5];
    f32x2 xr2[4] = {upk(xru.x), upk(xru.y), upk(xru.z), upk(xru.w)};
    const int beg = rowptr[n], end = rowptr[n + 1];
    float ssum = 0.f;
    f32x2 acc[4] = {};
    const f32x2 slope2 = {SLOPE, SLOPE};
    for (int i0 = beg; i0 < end; i0 += 2) {
        int i = i0 + sub;
        bool valid = i < end;
        int s = csrc[valid ? i : end - 1];
        uint4 xu = xl4[(size_t)s * 32 + l5];
        f32x2 xl2[4] = {upk(xu.x), upk(xu.y), upk(xu.z), upk(xu.w)};
        f32x2 tv2 = {0.f, 0.f};
        #pragma unroll
        for (int j = 0; j < 4; ++j) {
            f32x2 v = xl2[j] + xr2[j];
            v = __builtin_elementwise_max(v, v * slope2);   // leaky_relu
            tv2 = __builtin_elementwise_fma(v, aw[j], tv2);
        }
        float tv = tv2.x + tv2.y;
        tv += __shfl_xor(tv, 1);
        tv += __shfl_xor(tv, 2);
        tv += __shfl_xor(tv, 4);
        float p = valid ? __expf(tv) : 0.f;
        ssum += p;
        f32x2 p2 = {p, p};
        #pragma unroll
        for (int j = 0; j < 4; ++j)
            acc[j] = __builtin_elementwise_fma(p2, xl2[j], acc[j]);
    }
    // merge the two half-wave streams
    ssum += __shfl_xor(ssum, 32);
    float a[8] = {acc[0].x, acc[0].y, acc[1].x, acc[1].y,
                  acc[2].x, acc[2].y, acc[3].x, acc[3].y};
    #pragma unroll
    for (int j = 0; j < 8; ++j) a[j] += __shfl_xor(a[j], 32);
    float inv = 1.f / ssum;
    if (CONCAT) {
        if (sub == 0) {
            unsigned short r[8];
            #pragma unroll
            for (int j = 0; j < 8; ++j) r[j] = f2b(a[j] * inv);
            uint4 o;
            o.x = r[0] | ((unsigned)r[1] << 16); o.y = r[2] | ((unsigned)r[3] << 16);
            o.z = r[4] | ((unsigned)r[5] << 16); o.w = r[6] | ((unsigned)r[7] << 16);
            ((uint4*)outb)[(size_t)n * 32 + l5] = o;
        }
    } else {
        float v[8];
        #pragma unroll
        for (int j = 0; j < 8; ++j) {
            v[j] = a[j] * inv;
            v[j] += __shfl_xor(v[j], 8);
            v[j] += __shfl_xor(v[j], 16);
            v[j] *= 0.25f;
        }
        if (lane < 8) {
            ((float4*)outf)[(size_t)n * 16 + lane * 2]     = make_float4(v[0], v[1], v[2], v[3]);
            ((float4*)outf)[(size_t)n * 16 + lane * 2 + 1] = make_float4(v[4], v[5], v[6], v[7]);
        }
    }
}

// ---------------- BN stats, C=256, bf16 input, LDS pre-reduction ----------------
__global__ __launch_bounds__(256) void k_bnstats256b(const __hip_bfloat16* __restrict__ in,
                                                     float* __restrict__ stats) {
    __shared__ float sh[512];
    int r0 = blockIdx.x * 128;
    int rend = min(r0 + 128, NN);
    int t = threadIdx.x;
    int half = t >> 7, tc = t & 127;
    float s0 = 0.f, s1 = 0.f, q0 = 0.f, q1 = 0.f;
    const unsigned* u32 = (const unsigned*)in;
    for (int r = r0 + half; r < rend; r += 2) {
        unsigned w = u32[(size_t)r * 128 + tc];
        float a = b2f(w & 0xffffu), b = b2f(w >> 16);
        s0 += a; q0 += a * a; s1 += b; q1 += b * b;
    }
    if (half) {
        sh[tc * 4 + 0] = s0; sh[tc * 4 + 1] = s1;
        sh[tc * 4 + 2] = q0; sh[tc * 4 + 3] = q1;
    }
    __syncthreads();
    if (!half) {
        s0 += sh[tc * 4 + 0]; s1 += sh[tc * 4 + 1];
        q0 += sh[tc * 4 + 2]; q1 += sh[tc * 4 + 3];
        atomicAdd(&stats[2 * tc], s0);       atomicAdd(&stats[2 * tc + 1], s1);
        atomicAdd(&stats[256 + 2 * tc], q0); atomicAdd(&stats[256 + 2 * tc + 1], q1);
    }
}

// ---------------- BN + ELU, C=256, bf16 in -> bf16 out, x8 vectorized ----------------
__global__ __launch_bounds__(256) void k_bnelu256b(const __hip_bfloat16* __restrict__ in,
        const float* __restrict__ stats, const float* __restrict__ gamma,
        const float* __restrict__ beta, __hip_bfloat16* __restrict__ outb) {
    int id = blockIdx.x * 256 + threadIdx.x;
    if (id >= NN * 32) return;
    int c0 = (id & 31) * 8;
    uint4 u = ((const uint4*)in)[id];
    float f[8]; unpack8(u, f);
    unsigned short r[8];
    #pragma unroll
    for (int j = 0; j < 8; ++j) {
        int c = c0 + j;
        float mu  = stats[c] * (1.f / NN);
        float var = stats[256 + c] * (1.f / NN) - mu * mu;
        float w = gamma[c] * rsqrtf(var + EPSBN);
        float v = w * (f[j] - mu) + beta[c];
        v = (v > 0.f) ? v : (__expf(v) - 1.f);
        r[j] = f2b(v);
    }
    uint4 o;
    o.x = r[0] | ((unsigned)r[1] << 16); o.y = r[2] | ((unsigned)r[3] << 16);
    o.z = r[4] | ((unsigned)r[5] << 16); o.w = r[6] | ((unsigned)r[7] << 16);
    ((uint4*)outb)[id] = o;
}

// ---------------- BN stats for final layer (C=64, fp32) ----------------
__global__ void k_bnstats64(const float* __restrict__ h, float* __restrict__ stats) {
    int r0 = blockIdx.x * 128;
    int rend = min(r0 + 128, NN);
    int c = threadIdx.x & 63;
    int ro = threadIdx.x >> 6;
    float s = 0.f, q = 0.f;
    for (int r = r0 + ro; r < rend; r += 4) {
        float v = h[(size_t)r * 64 + c];
        s += v; q += v * v;
    }
    atomicAdd(&stats[c], s); atomicAdd(&stats[64 + c], q);
}

// ---------------- fused BN+ELU + global mean pool (batch sorted) ----------------
__global__ void k_pool(const float* __restrict__ h, const int* __restrict__ batch,
                       const float* __restrict__ stats, const float* __restrict__ gamma,
                       const float* __restrict__ beta,
                       float* __restrict__ pooled, float* __restrict__ cnt) {
    int wv = threadIdx.x >> 6, lane = threadIdx.x & 63;
    int w = blockIdx.x * 4 + wv;
    int n0 = w * 64;
    if (n0 >= NN) return;
    int n1 = min(n0 + 64, NN);
    float mu  = stats[lane] * (1.f / NN);
    float var = stats[64 + lane] * (1.f / NN) - mu * mu;
    float sc = gamma[lane] * rsqrtf(var + EPSBN);
    float sh = beta[lane] - mu * sc;
    float sum = 0.f;
    int cur = batch[n0], c = 0;
    for (int n = n0; n < n1; ++n) {
        int g = batch[n];
        if (g != cur) {
            atomicAdd(&pooled[cur * 64 + lane], sum);
            if (lane == 0) atomicAdd(&cnt[cur], (float)c);
            sum = 0.f; c = 0; cur = g;
        }
        float v = fmaf(h[(size_t)n * 64 + lane], sc, sh);
        v = (v > 0.f) ? v : (__expf(v) - 1.f);
        sum += v;
        ++c;
    }
    atomicAdd(&pooled[cur * 64 + lane], sum);
    if (lane == 0) atomicAdd(&cnt[cur], (float)c);
}

__global__ void k_mlp(const float* __restrict__ pooled, const float* __restrict__ cnt,
        const float* __restrict__ w1, const float* __restrict__ b1,
        const float* __restrict__ w2, const float* __restrict__ b2,
        float* __restrict__ out) {
    __shared__ float p[64], o[64];
    int g = blockIdx.x, t = threadIdx.x;
    float c = fmaxf(cnt[g], 1.f);
    p[t] = pooled[g * 64 + t] / c;
    __syncthreads();
    float s = b1[t];
    for (int k = 0; k < 64; ++k) s += p[k] * w1[k * 64 + t];
    o[t] = fmaxf(s, 0.f);
    __syncthreads();
    if (t < NCL) {
        float s2 = b2[t];
        for (int k = 0; k < 64; ++k) s2 += o[k] * w2[k * NCL + t];
        out[g * NCL + t] = s2;
    }
}

extern "C" void kernel_launch(void* const* d_in, const int* in_sizes, int n_in,
                              void* d_out, int out_size, void* d_ws, size_t ws_size,
                              hipStream_t stream) {
    const float* x     = (const float*)d_in[0];
    const int*   ei    = (const int*)d_in[1];
    const int*   batch = (const int*)d_in[2];
    WPtrs wp;
    const float *attp[4], *bng[4], *bnb[4];
    for (int i = 0; i < 4; ++i) {
        wp.wl[i] = (const float*)d_in[3 + 6 * i];
        wp.wr[i] = (const float*)d_in[4 + 6 * i];
        attp[i]  = (const float*)d_in[5 + 6 * i];
        bng[i]   = (const float*)d_in[7 + 6 * i];
        bnb[i]   = (const float*)d_in[8 + 6 * i];
    }
    const float* fc1w = (const float*)d_in[27];
    const float* fc1b = (const float*)d_in[28];
    const float* fc2w = (const float*)d_in[29];
    const float* fc2b = (const float*)d_in[30];
    float* out = (float*)d_out;

    char* w = (char*)d_ws;
    __hip_bfloat16* xlb  = (__hip_bfloat16*)w; w += (size_t)MPAD * CC * 2;
    __hip_bfloat16* xrb  = (__hip_bfloat16*)w; w += (size_t)MPAD * CC * 2;
    __hip_bfloat16* bufB = (__hip_bfloat16*)w; w += (size_t)MPAD * CC * 2;  // gat concat out
    __hip_bfloat16* hb   = (__hip_bfloat16*)w; w += (size_t)MPAD * CC * 2;  // GEMM input
    __hip_bfloat16* wt   = (__hip_bfloat16*)w; w += (size_t)458752 * 2;     // all Wt
    float* bufF   = (float*)w; w += (size_t)NN * HIDD * 4;  // layer-3 gat out (raw)
    int*   rowptr = (int*)w;   w += (size_t)(NN + 1) * 4;
    int*   cursor = (int*)w;   w += (size_t)(NN + 1) * 4;
    int*   csrc   = (int*)w;   w += (size_t)ETOT * 4;
    // single-memset zero block:
    char* zbase = w;
    int*   deg       = (int*)w;   w += (size_t)NN * 4;
    float* stats_all = (float*)w; w += (size_t)4 * 512 * 4;
    float* pooled    = (float*)w; w += (size_t)GG * HIDD * 4;
    float* cnt       = (float*)w; w += (size_t)GG * 4;
    size_t zbytes = (size_t)(w - zbase);

    __hip_bfloat16* Wt[4];
    Wt[0] = wt;
    Wt[1] = wt + 65536;
    Wt[2] = wt + 65536 + 131072;
    Wt[3] = wt + 65536 + 262144;

    hipMemsetAsync(zbase, 0, zbytes, stream);
    k_setup<<<(ETOT + 458752 + NN * IND + 255) / 256, 256, 0, stream>>>(ei, deg, wp, x, wt, hb);
    k_scan<<<1, 1024, 0, stream>>>(deg, rowptr, cursor);
    k_scatter<<<(ETOT + 255) / 256, 256, 0, stream>>>(ei, cursor, csrc);

    for (int L = 0; L < 4; ++L) {
        float* stats = stats_all + 512 * L;
        dim3 gg(MPAD / 128, 4);
        if (L == 0) k_gemm_mfma<IND><<<gg, 256, 0, stream>>>(hb, Wt[0], xlb, xrb);
        else        k_gemm_mfma<CC><<<gg, 256, 0, stream>>>(hb, Wt[L], xlb, xrb);
        if (L < 3) {
            k_gat<true><<<NN / 4, 256, 0, stream>>>(xlb, xrb, rowptr, csrc, attp[L], bufB, nullptr);
            k_bnstats256b<<<(NN + 127) / 128, 256, 0, stream>>>(bufB, stats);
            k_bnelu256b<<<(NN * 32 + 255) / 256, 256, 0, stream>>>(bufB, stats, bng[L], bnb[L], hb);
        } else {
            k_gat<false><<<NN / 4, 256, 0, stream>>>(xlb, xrb, rowptr, csrc, attp[3], nullptr, bufF);
            k_bnstats64<<<(NN + 127) / 128, 256, 0, stream>>>(bufF, stats);
        }
    }
    k_pool<<<((NN + 63) / 64 + 3) / 4, 256, 0, stream>>>(bufF, batch, stats_all + 512 * 3,
                                                         bng[3], bnb[3], pooled, cnt);
    k_mlp<<<GG, 64, 0, stream>>>(pooled, cnt, fc1w, fc1b, fc2w, fc2b, out);
}

// Round 7
// 594.158 us; speedup vs baseline: 1.1877x; 1.1877x over previous
//
#include <hip/hip_runtime.h>
#include <hip/hip_bf16.h>
#include <math.h>

#define NN    30000
#define MPAD  30080   // 235*128, padded row count for bounds-check-free GEMM
#define EE    300000
#define ETOT  330000
#define GG    128
#define IND   128
#define HIDD  64
#define NHEAD 4
#define CC    256     // HEADS*HID
#define NCL   10
#define EPSBN 1e-5f
#define SLOPE 0.2f

typedef __attribute__((ext_vector_type(8))) __bf16 bf16x8;
typedef __attribute__((ext_vector_type(4))) float f32x4;
typedef __attribute__((ext_vector_type(2))) float f32x2;

__device__ inline float b2f(unsigned u16) {
    union { unsigned i; float f; } c; c.i = u16 << 16; return c.f;
}
__device__ inline unsigned short f2b(float f) {
    __hip_bfloat16 b = __float2bfloat16(f);
    unsigned short u; __builtin_memcpy(&u, &b, 2); return u;
}
__device__ inline f32x2 upk(unsigned u) {     // 2 packed bf16 -> f32x2
    union { unsigned i; float f; } lo, hi;
    lo.i = u << 16;
    hi.i = u & 0xffff0000u;
    f32x2 r; r.x = lo.f; r.y = hi.f; return r;
}
__device__ inline void unpack8(uint4 u, float* f) {
    f[0] = b2f(u.x & 0xffffu); f[1] = b2f(u.x >> 16);
    f[2] = b2f(u.y & 0xffffu); f[3] = b2f(u.y >> 16);
    f[4] = b2f(u.z & 0xffffu); f[5] = b2f(u.z >> 16);
    f[6] = b2f(u.w & 0xffffu); f[7] = b2f(u.w >> 16);
}

// ---------------- fused: degree histogram + weight prep + x conversion ----------------
struct WPtrs { const float* wl[4]; const float* wr[4]; };

__global__ void k_setup(const int* __restrict__ ei, int* __restrict__ deg,
                        WPtrs p, const float* __restrict__ x,
                        __hip_bfloat16* __restrict__ wt, __hip_bfloat16* __restrict__ hb) {
    int id = blockIdx.x * 256 + threadIdx.x;
    if (id < ETOT) {
        int d = (id < EE) ? ei[EE + id] : (id - EE);
        atomicAdd(&deg[d], 1);
        return;
    }
    int id1 = id - ETOT;
    if (id1 < 65536) {                       // layer 0 W: [512][128]
        int n = id1 >> 7, k = id1 & 127;
        float v = (n < 256) ? p.wl[0][(size_t)k * 256 + n] : p.wr[0][(size_t)k * 256 + n - 256];
        wt[id1] = __float2bfloat16(v);
    } else if (id1 < 458752) {               // layers 1-3 W: [512][256]
        int id2 = id1 - 65536;
        int li = 1 + (id2 >> 17);
        int r = id2 & 131071;
        int n = r >> 8, k = r & 255;
        float v = (n < 256) ? p.wl[li][(size_t)k * 256 + n] : p.wr[li][(size_t)k * 256 + n - 256];
        wt[id1] = __float2bfloat16(v);
    } else {
        int id2 = id1 - 458752;
        if (id2 < NN * IND) hb[id2] = __float2bfloat16(x[id2]);
    }
}

__global__ void k_scan(const int* __restrict__ deg, int* __restrict__ rowptr,
                       int* __restrict__ cursor) {
    const int PER = 30;
    int t = threadIdx.x;
    int base = t * PER;
    int loc[PER];
    int s = 0;
    #pragma unroll
    for (int j = 0; j < PER; ++j) {
        int v = (base + j < NN) ? deg[base + j] : 0;
        loc[j] = s; s += v;
    }
    int lane = t & 63, wid = t >> 6;
    int v = s;
    #pragma unroll
    for (int d = 1; d < 64; d <<= 1) {
        int u = __shfl_up(v, d, 64);
        if (lane >= d) v += u;
    }
    __shared__ int wsum[16], woff[16];
    if (lane == 63) wsum[wid] = v;
    __syncthreads();
    if (t == 0) { int a = 0; for (int w2 = 0; w2 < 16; ++w2) { woff[w2] = a; a += wsum[w2]; } }
    __syncthreads();
    int excl = woff[wid] + (v - s);
    #pragma unroll
    for (int j = 0; j < PER; ++j) {
        int idx = base + j;
        if (idx <= NN) { int val = excl + loc[j]; rowptr[idx] = val; cursor[idx] = val; }
    }
}

__global__ void k_scatter(const int* __restrict__ ei, int* __restrict__ cursor,
                          int* __restrict__ csrc) {
    int e = blockIdx.x * blockDim.x + threadIdx.x;
    if (e >= ETOT) return;
    int s, d;
    if (e < EE) { s = ei[e]; d = ei[EE + e]; } else { s = e - EE; d = s; }
    int pos = atomicAdd(&cursor[d], 1);
    csrc[pos] = s;
}

// ---------------- bf16 MFMA GEMM, BK=32 (round-5 known-good): [MPAD,K]@[K,512] ----------------
// Rows padded to MPAD: no bounds checks. Staging software-pipelined.
// NOTE: BK=64 variant regressed 2x (31% occupancy -> store-merge failure, 5x write amp).
template<int K>
__global__ __launch_bounds__(256) void k_gemm_mfma(
        const __hip_bfloat16* __restrict__ A, const __hip_bfloat16* __restrict__ Wt,
        __hip_bfloat16* __restrict__ xlb, __hip_bfloat16* __restrict__ xrb) {
    __shared__ __bf16 As[128 * 40];   // [row][k] pad 32->40 (80B stride, 16B aligned)
    __shared__ __bf16 Bs[128 * 40];
    const int t = threadIdx.x;
    const int row0 = blockIdx.x * 128;
    const int col0 = blockIdx.y * 128;
    const int wv = t >> 6, lane = t & 63;
    const int wm = (wv & 1) * 64, wn = (wv >> 1) * 64;
    const int lm = lane & 15, lq = lane >> 4;
    const int sr0 = t >> 2, scc = (t & 3) * 8;       // staging: row, col offset
    const int sr1 = sr0 + 64;
    uint4 va0, va1, vb0, vb1;
    va0 = *(const uint4*)&A [(size_t)(row0 + sr0) * K + scc];
    va1 = *(const uint4*)&A [(size_t)(row0 + sr1) * K + scc];
    vb0 = *(const uint4*)&Wt[(size_t)(col0 + sr0) * K + scc];
    vb1 = *(const uint4*)&Wt[(size_t)(col0 + sr1) * K + scc];
    f32x4 acc[4][4] = {};
    for (int k0 = 0; k0 < K; k0 += 32) {
        *(uint4*)&As[sr0 * 40 + scc] = va0;
        *(uint4*)&As[sr1 * 40 + scc] = va1;
        *(uint4*)&Bs[sr0 * 40 + scc] = vb0;
        *(uint4*)&Bs[sr1 * 40 + scc] = vb1;
        __syncthreads();
        if (k0 + 32 < K) {
            int kn = k0 + 32;
            va0 = *(const uint4*)&A [(size_t)(row0 + sr0) * K + kn + scc];
            va1 = *(const uint4*)&A [(size_t)(row0 + sr1) * K + kn + scc];
            vb0 = *(const uint4*)&Wt[(size_t)(col0 + sr0) * K + kn + scc];
            vb1 = *(const uint4*)&Wt[(size_t)(col0 + sr1) * K + kn + scc];
        }
        bf16x8 af[4], bfr[4];
        #pragma unroll
        for (int i = 0; i < 4; ++i) {
            af[i]  = *(bf16x8*)&As[(wm + i * 16 + lm) * 40 + lq * 8];
            bfr[i] = *(bf16x8*)&Bs[(wn + i * 16 + lm) * 40 + lq * 8];
        }
        #pragma unroll
        for (int i = 0; i < 4; ++i)
            #pragma unroll
            for (int j = 0; j < 4; ++j)
                acc[i][j] = __builtin_amdgcn_mfma_f32_16x16x32_bf16(af[i], bfr[j], acc[i][j], 0, 0, 0);
        __syncthreads();
    }
    const int crow = lq * 4;
    __hip_bfloat16* O = (blockIdx.y < 2) ? xlb : xrb;
    const int cbase = (blockIdx.y & 1) * 128 + wn;
    #pragma unroll
    for (int j = 0; j < 4; ++j) {
        int oc = cbase + j * 16 + lm;
        #pragma unroll
        for (int i = 0; i < 4; ++i) {
            int grow = row0 + wm + i * 16 + crow;
            #pragma unroll
            for (int r = 0; r < 4; ++r)
                O[(size_t)(grow + r) * CC + oc] = __float2bfloat16(acc[i][j][r]);
        }
    }
}

// ---------------- GATv2: one wave per dst, 2 edges/iter, packed-f32 math ----------------
template<bool CONCAT>
__global__ __launch_bounds__(256) void k_gat(const __hip_bfloat16* __restrict__ xlb,
        const __hip_bfloat16* __restrict__ xrb, const int* __restrict__ rowptr,
        const int* __restrict__ csrc, const float* __restrict__ att,
        __hip_bfloat16* __restrict__ outb, float* __restrict__ outf) {
    const int wv = threadIdx.x >> 6, lane = threadIdx.x & 63;
    const int n = blockIdx.x * 4 + wv;
    if (n >= NN) return;
    const int sub = lane >> 5, l5 = lane & 31;
    const float4* att4 = (const float4*)att;
    float4 a0 = att4[l5 * 2], a1 = att4[l5 * 2 + 1];
    f32x2 aw[4];
    aw[0].x = a0.x; aw[0].y = a0.y; aw[1].x = a0.z; aw[1].y = a0.w;
    aw[2].x = a1.x; aw[2].y = a1.y; aw[3].x = a1.z; aw[3].y = a1.w;
    const uint4* xl4 = (const uint4*)xlb;
    const uint4* xr4 = (const uint4*)xrb;
    uint4 xru = xr4[(size_t)n * 32 + l5];
    f32x2 xr2[4] = {upk(xru.x), upk(xru.y), upk(xru.z), upk(xru.w)};
    const int beg = rowptr[n], end = rowptr[n + 1];
    float ssum = 0.f;
    f32x2 acc[4] = {};
    const f32x2 slope2 = {SLOPE, SLOPE};
    for (int i0 = beg; i0 < end; i0 += 2) {
        int i = i0 + sub;
        bool valid = i < end;
        int s = csrc[valid ? i : end - 1];
        uint4 xu = xl4[(size_t)s * 32 + l5];
        f32x2 xl2[4] = {upk(xu.x), upk(xu.y), upk(xu.z), upk(xu.w)};
        f32x2 tv2 = {0.f, 0.f};
        #pragma unroll
        for (int j = 0; j < 4; ++j) {
            f32x2 v = xl2[j] + xr2[j];
            v = __builtin_elementwise_max(v, v * slope2);   // leaky_relu
            tv2 = __builtin_elementwise_fma(v, aw[j], tv2);
        }
        float tv = tv2.x + tv2.y;
        tv += __shfl_xor(tv, 1);
        tv += __shfl_xor(tv, 2);
        tv += __shfl_xor(tv, 4);
        float p = valid ? __expf(tv) : 0.f;
        ssum += p;
        f32x2 p2 = {p, p};
        #pragma unroll
        for (int j = 0; j < 4; ++j)
            acc[j] = __builtin_elementwise_fma(p2, xl2[j], acc[j]);
    }
    // merge the two half-wave streams
    ssum += __shfl_xor(ssum, 32);
    float a[8] = {acc[0].x, acc[0].y, acc[1].x, acc[1].y,
                  acc[2].x, acc[2].y, acc[3].x, acc[3].y};
    #pragma unroll
    for (int j = 0; j < 8; ++j) a[j] += __shfl_xor(a[j], 32);
    float inv = 1.f / ssum;
    if (CONCAT) {
        if (sub == 0) {
            unsigned short r[8];
            #pragma unroll
            for (int j = 0; j < 8; ++j) r[j] = f2b(a[j] * inv);
            uint4 o;
            o.x = r[0] | ((unsigned)r[1] << 16); o.y = r[2] | ((unsigned)r[3] << 16);
            o.z = r[4] | ((unsigned)r[5] << 16); o.w = r[6] | ((unsigned)r[7] << 16);
            ((uint4*)outb)[(size_t)n * 32 + l5] = o;
        }
    } else {
        float v[8];
        #pragma unroll
        for (int j = 0; j < 8; ++j) {
            v[j] = a[j] * inv;
            v[j] += __shfl_xor(v[j], 8);
            v[j] += __shfl_xor(v[j], 16);
            v[j] *= 0.25f;
        }
        if (lane < 8) {
            ((float4*)outf)[(size_t)n * 16 + lane * 2]     = make_float4(v[0], v[1], v[2], v[3]);
            ((float4*)outf)[(size_t)n * 16 + lane * 2 + 1] = make_float4(v[4], v[5], v[6], v[7]);
        }
    }
}

// ---------------- BN stats, C=256, bf16 input, LDS pre-reduction ----------------
__global__ __launch_bounds__(256) void k_bnstats256b(const __hip_bfloat16* __restrict__ in,
                                                     float* __restrict__ stats) {
    __shared__ float sh[512];
    int r0 = blockIdx.x * 128;
    int rend = min(r0 + 128, NN);
    int t = threadIdx.x;
    int half = t >> 7, tc = t & 127;
    float s0 = 0.f, s1 = 0.f, q0 = 0.f, q1 = 0.f;
    const unsigned* u32 = (const unsigned*)in;
    for (int r = r0 + half; r < rend; r += 2) {
        unsigned w = u32[(size_t)r * 128 + tc];
        float a = b2f(w & 0xffffu), b = b2f(w >> 16);
        s0 += a; q0 += a * a; s1 += b; q1 += b * b;
    }
    if (half) {
        sh[tc * 4 + 0] = s0; sh[tc * 4 + 1] = s1;
        sh[tc * 4 + 2] = q0; sh[tc * 4 + 3] = q1;
    }
    __syncthreads();
    if (!half) {
        s0 += sh[tc * 4 + 0]; s1 += sh[tc * 4 + 1];
        q0 += sh[tc * 4 + 2]; q1 += sh[tc * 4 + 3];
        atomicAdd(&stats[2 * tc], s0);       atomicAdd(&stats[2 * tc + 1], s1);
        atomicAdd(&stats[256 + 2 * tc], q0); atomicAdd(&stats[256 + 2 * tc + 1], q1);
    }
}

// ---------------- BN + ELU, C=256, bf16 in -> bf16 out, x8 vectorized ----------------
__global__ __launch_bounds__(256) void k_bnelu256b(const __hip_bfloat16* __restrict__ in,
        const float* __restrict__ stats, const float* __restrict__ gamma,
        const float* __restrict__ beta, __hip_bfloat16* __restrict__ outb) {
    int id = blockIdx.x * 256 + threadIdx.x;
    if (id >= NN * 32) return;
    int c0 = (id & 31) * 8;
    uint4 u = ((const uint4*)in)[id];
    float f[8]; unpack8(u, f);
    unsigned short r[8];
    #pragma unroll
    for (int j = 0; j < 8; ++j) {
        int c = c0 + j;
        float mu  = stats[c] * (1.f / NN);
        float var = stats[256 + c] * (1.f / NN) - mu * mu;
        float w = gamma[c] * rsqrtf(var + EPSBN);
        float v = w * (f[j] - mu) + beta[c];
        v = (v > 0.f) ? v : (__expf(v) - 1.f);
        r[j] = f2b(v);
    }
    uint4 o;
    o.x = r[0] | ((unsigned)r[1] << 16); o.y = r[2] | ((unsigned)r[3] << 16);
    o.z = r[4] | ((unsigned)r[5] << 16); o.w = r[6] | ((unsigned)r[7] << 16);
    ((uint4*)outb)[id] = o;
}

// ---------------- BN stats for final layer (C=64, fp32) ----------------
__global__ void k_bnstats64(const float* __restrict__ h, float* __restrict__ stats) {
    int r0 = blockIdx.x * 128;
    int rend = min(r0 + 128, NN);
    int c = threadIdx.x & 63;
    int ro = threadIdx.x >> 6;
    float s = 0.f, q = 0.f;
    for (int r = r0 + ro; r < rend; r += 4) {
        float v = h[(size_t)r * 64 + c];
        s += v; q += v * v;
    }
    atomicAdd(&stats[c], s); atomicAdd(&stats[64 + c], q);
}

// ---------------- fused BN+ELU + global mean pool (batch sorted) ----------------
__global__ void k_pool(const float* __restrict__ h, const int* __restrict__ batch,
                       const float* __restrict__ stats, const float* __restrict__ gamma,
                       const float* __restrict__ beta,
                       float* __restrict__ pooled, float* __restrict__ cnt) {
    int wv = threadIdx.x >> 6, lane = threadIdx.x & 63;
    int w = blockIdx.x * 4 + wv;
    int n0 = w * 64;
    if (n0 >= NN) return;
    int n1 = min(n0 + 64, NN);
    float mu  = stats[lane] * (1.f / NN);
    float var = stats[64 + lane] * (1.f / NN) - mu * mu;
    float sc = gamma[lane] * rsqrtf(var + EPSBN);
    float sh = beta[lane] - mu * sc;
    float sum = 0.f;
    int cur = batch[n0], c = 0;
    for (int n = n0; n < n1; ++n) {
        int g = batch[n];
        if (g != cur) {
            atomicAdd(&pooled[cur * 64 + lane], sum);
            if (lane == 0) atomicAdd(&cnt[cur], (float)c);
            sum = 0.f; c = 0; cur = g;
        }
        float v = fmaf(h[(size_t)n * 64 + lane], sc, sh);
        v = (v > 0.f) ? v : (__expf(v) - 1.f);
        sum += v;
        ++c;
    }
    atomicAdd(&pooled[cur * 64 + lane], sum);
    if (lane == 0) atomicAdd(&cnt[cur], (float)c);
}

__global__ void k_mlp(const float* __restrict__ pooled, const float* __restrict__ cnt,
        const float* __restrict__ w1, const float* __restrict__ b1,
        const float* __restrict__ w2, const float* __restrict__ b2,
        float* __restrict__ out) {
    __shared__ float p[64], o[64];
    int g = blockIdx.x, t = threadIdx.x;
    float c = fmaxf(cnt[g], 1.f);
    p[t] = pooled[g * 64 + t] / c;
    __syncthreads();
    float s = b1[t];
    for (int k = 0; k < 64; ++k) s += p[k] * w1[k * 64 + t];
    o[t] = fmaxf(s, 0.f);
    __syncthreads();
    if (t < NCL) {
        float s2 = b2[t];
        for (int k = 0; k < 64; ++k) s2 += o[k] * w2[k * NCL + t];
        out[g * NCL + t] = s2;
    }
}

extern "C" void kernel_launch(void* const* d_in, const int* in_sizes, int n_in,
                              void* d_out, int out_size, void* d_ws, size_t ws_size,
                              hipStream_t stream) {
    const float* x     = (const float*)d_in[0];
    const int*   ei    = (const int*)d_in[1];
    const int*   batch = (const int*)d_in[2];
    WPtrs wp;
    const float *attp[4], *bng[4], *bnb[4];
    for (int i = 0; i < 4; ++i) {
        wp.wl[i] = (const float*)d_in[3 + 6 * i];
        wp.wr[i] = (const float*)d_in[4 + 6 * i];
        attp[i]  = (const float*)d_in[5 + 6 * i];
        bng[i]   = (const float*)d_in[7 + 6 * i];
        bnb[i]   = (const float*)d_in[8 + 6 * i];
    }
    const float* fc1w = (const float*)d_in[27];
    const float* fc1b = (const float*)d_in[28];
    const float* fc2w = (const float*)d_in[29];
    const float* fc2b = (const float*)d_in[30];
    float* out = (float*)d_out;

    char* w = (char*)d_ws;
    __hip_bfloat16* xlb  = (__hip_bfloat16*)w; w += (size_t)MPAD * CC * 2;
    __hip_bfloat16* xrb  = (__hip_bfloat16*)w; w += (size_t)MPAD * CC * 2;
    __hip_bfloat16* bufB = (__hip_bfloat16*)w; w += (size_t)MPAD * CC * 2;  // gat concat out
    __hip_bfloat16* hb   = (__hip_bfloat16*)w; w += (size_t)MPAD * CC * 2;  // GEMM input
    __hip_bfloat16* wt   = (__hip_bfloat16*)w; w += (size_t)458752 * 2;     // all Wt
    float* bufF   = (float*)w; w += (size_t)NN * HIDD * 4;  // layer-3 gat out (raw)
    int*   rowptr = (int*)w;   w += (size_t)(NN + 1) * 4;
    int*   cursor = (int*)w;   w += (size_t)(NN + 1) * 4;
    int*   csrc   = (int*)w;   w += (size_t)ETOT * 4;
    // single-memset zero block:
    char* zbase = w;
    int*   deg       = (int*)w;   w += (size_t)NN * 4;
    float* stats_all = (float*)w; w += (size_t)4 * 512 * 4;
    float* pooled    = (float*)w; w += (size_t)GG * HIDD * 4;
    float* cnt       = (float*)w; w += (size_t)GG * 4;
    size_t zbytes = (size_t)(w - zbase);

    __hip_bfloat16* Wt[4];
    Wt[0] = wt;
    Wt[1] = wt + 65536;
    Wt[2] = wt + 65536 + 131072;
    Wt[3] = wt + 65536 + 262144;

    hipMemsetAsync(zbase, 0, zbytes, stream);
    k_setup<<<(ETOT + 458752 + NN * IND + 255) / 256, 256, 0, stream>>>(ei, deg, wp, x, wt, hb);
    k_scan<<<1, 1024, 0, stream>>>(deg, rowptr, cursor);
    k_scatter<<<(ETOT + 255) / 256, 256, 0, stream>>>(ei, cursor, csrc);

    for (int L = 0; L < 4; ++L) {
        float* stats = stats_all + 512 * L;
        dim3 gg(MPAD / 128, 4);
        if (L == 0) k_gemm_mfma<IND><<<gg, 256, 0, stream>>>(hb, Wt[0], xlb, xrb);
        else        k_gemm_mfma<CC><<<gg, 256, 0, stream>>>(hb, Wt[L], xlb, xrb);
        if (L < 3) {
            k_gat<true><<<NN / 4, 256, 0, stream>>>(xlb, xrb, rowptr, csrc, attp[L], bufB, nullptr);
            k_bnstats256b<<<(NN + 127) / 128, 256, 0, stream>>>(bufB, stats);
            k_bnelu256b<<<(NN * 32 + 255) / 256, 256, 0, stream>>>(bufB, stats, bng[L], bnb[L], hb);
        } else {
            k_gat<false><<<NN / 4, 256, 0, stream>>>(xlb, xrb, rowptr, csrc, attp[3], nullptr, bufF);
            k_bnstats64<<<(NN + 127) / 128, 256, 0, stream>>>(bufF, stats);
        }
    }
    k_pool<<<((NN + 63) / 64 + 3) / 4, 256, 0, stream>>>(bufF, batch, stats_all + 512 * 3,
                                                         bng[3], bnb[3], pooled, cnt);
    k_mlp<<<GG, 64, 0, stream>>>(pooled, cnt, fc1w, fc1b, fc2w, fc2b, out);
}